// Round 5
// baseline (460.642 us; speedup 1.0000x reference)
//
#include <hip/hip_runtime.h>

// Problem constants (fixed by the reference).
#define NGRID 262144      // N = 64^3 = 2^18
#define NNZ_C 1835008     // 7 * N
#define TP    260         // prep LDS row stride (floats); 260*4 ≡ 0 mod 16
#define NS    128         // k_post n-slice per block
#define TPAD  132         // k_post LDS row stride (floats); 132*4 ≡ 0 mod 16,
                          // 132 ≡ 260 ≡ 4 (mod 32): same (benign) bank profile

// Fixed-point scale for packed-pair atomic accumulation of yat.
// |value| bound before low-lane overflow: 2^31/2^19 = 4096 (typ |sum| < 50).
#define FPSCALE   524288.0f          // 2^19
#define FPINV     (1.0f / 524288.0f)

// Loss closed form:  loss = mean_b( Stt - 2a*C2 + a^2*C3 ),  a = Sty/C1
//   C1=<yp,yat>  C2=<yt,yat>  C3=<yat,yat>  Stt=<yt,yt>  Sty=<yt,yp>
// R4 post-mortem: u64 atomic = 1.65 cy/op at TCC (f32 = 1.00); scatter
// 163.8us with 29.4M ops. This round: (1) scatter 8 lanes/edge (half the
// gather+atomic INSTRUCTIONS, same TCC ops) - diagnostic for issue-bound
// component; (2) k_post NS=128, 2048 blocks, 16.9KB LDS (~9 blocks/CU).

// ---------------------------------------------------------------------------
// K1: yp transpose (R7-green tile construct) + zero yat. grid = 1024 x 256.
// ---------------------------------------------------------------------------
__global__ __launch_bounds__(256) void k_prep(
        const float* __restrict__ yp, float* __restrict__ yp_t,
        float* __restrict__ yat_t) {
    __shared__ __align__(16) float T[32 * TP];
    const int tid = threadIdx.x;
    const int l = tid & 63, w = tid >> 6;
    const size_t n0 = (size_t)blockIdx.x * 256;
    #pragma unroll
    for (int s = 0; s < 8; ++s) {
        const int b = s * 4 + w;                 // unique (s,w) -> 0..31
        const float4 a = *(const float4*)(yp + (size_t)b * NGRID + n0 + 4 * l);
        *(float4*)(&T[b * TP + 4 * l]) = a;      // ds_write_b128, row b
    }
    __syncthreads();
    float4* dst4 = (float4*)(yp_t + n0 * 32);
    float4* yat4 = (float4*)(yat_t + n0 * 32);
    #pragma unroll
    for (int q = 0; q < 8; ++q) {
        const int f = q * 256 + tid;             // float4 index, 0..2047
        const int n = f >> 3;                    // 0..255 local n
        const int bb = 4 * (f & 7);              // base batch of this quad
        float4 v;
        v.x = T[(bb + 0) * TP + n];
        v.y = T[(bb + 1) * TP + n];
        v.z = T[(bb + 2) * TP + n];
        v.w = T[(bb + 3) * TP + n];
        dst4[f] = v;                             // coalesced 1 KB/wave
        yat4[f] = make_float4(0.f, 0.f, 0.f, 0.f);
    }
}

// ---------------------------------------------------------------------------
// K2: COO scatter, packed pairs, 8 lanes/edge. thread -> (e=tid>>3,
// b4=tid&7): float4 gather of batches 4b4..4b4+3 from yp_t row c (8 lanes
// x 16B = full 128B line), fixed-point convert, TWO u64 atomics. Same
// 29.4M TCC ops as R4 but half the memory/atomic instruction count.
// grid = NNZ*8/256 = 57344 blocks.
// ---------------------------------------------------------------------------
__global__ void k_scatter(const float* __restrict__ vals,
                          const int* __restrict__ rows,
                          const int* __restrict__ cols,
                          const float* __restrict__ yp_t,
                          unsigned long long* __restrict__ yat64) {
    const size_t tid = (size_t)blockIdx.x * blockDim.x + threadIdx.x;
    const int b4 = (int)(tid & 7);
    const size_t e = tid >> 3;
    const float v = vals[e];
    const int r = rows[e];
    const int c = cols[e];
    const float4 x4 = *(const float4*)(yp_t + (size_t)c * 32 + 4 * b4);
    const long long i0 = (long long)__float2int_rn(v * x4.x * FPSCALE);
    const long long i1 = (long long)__float2int_rn(v * x4.y * FPSCALE);
    const long long i2 = (long long)__float2int_rn(v * x4.z * FPSCALE);
    const long long i3 = (long long)__float2int_rn(v * x4.w * FPSCALE);
    unsigned long long* dst = &yat64[(size_t)r * 16 + 2 * b4];
    atomicAdd(dst, (unsigned long long)((i1 << 32) + i0));
    atomicAdd(dst + 1, (unsigned long long)((i3 << 32) + i2));
}

// ---------------------------------------------------------------------------
// K3: post-pass, mixed-layout. Block g owns n-slice [128g, 128g+128).
//   Phase A: load packed yat tile (128 x 16 u64, coalesced ulonglong2),
//            exact int64 unpack -> f32, LDS transposed T[b][n], TPAD=132.
//   Phase B: thread (b=tid>>3, j=tid&7): 4 float4 steps over n; yt/yp in
//            ORIGINAL (32,N) layout + ds_read_b128 from T; shfl-reduce
//            the 8 lanes per batch. 16.9 KB LDS -> ~9 blocks/CU.
// ---------------------------------------------------------------------------
__global__ __launch_bounds__(256) void k_post(
        const unsigned long long* __restrict__ yat64,
        const float* __restrict__ yp, const float* __restrict__ yt,
        float* __restrict__ p2) {
    __shared__ __align__(16) float T[32 * TPAD];     // 16.9 KB
    const int tid = threadIdx.x;
    const int g = blockIdx.x;                    // 0..2047
    const size_t n0 = (size_t)g * NS;
    const ulonglong2* y2 = (const ulonglong2*)(yat64 + n0 * 16);
    #pragma unroll
    for (int q = 0; q < 4; ++q) {
        const int f = q * 256 + tid;             // 0..1023 (ull2 index)
        const int n = f >> 3;                    // 0..127
        const int b0 = 4 * (f & 7);
        const ulonglong2 pv = y2[f];
        // exact unpack: p = h*2^32 + lo (lo signed); h = (p + 2^31) >> 32
        const int lo0 = (int)(unsigned)pv.x;
        const int hi0 = (int)((pv.x + 0x80000000ULL) >> 32);
        const int lo1 = (int)(unsigned)pv.y;
        const int hi1 = (int)((pv.y + 0x80000000ULL) >> 32);
        T[(b0 + 0) * TPAD + n] = (float)lo0 * FPINV;
        T[(b0 + 1) * TPAD + n] = (float)hi0 * FPINV;
        T[(b0 + 2) * TPAD + n] = (float)lo1 * FPINV;
        T[(b0 + 3) * TPAD + n] = (float)hi1 * FPINV;
    }
    __syncthreads();
    const int b = tid >> 3, j = tid & 7;
    const float* ytb = yt + (size_t)b * NGRID + n0;
    const float* ypb = yp + (size_t)b * NGRID + n0;
    const float* Tb = &T[b * TPAD];
    float c1 = 0.f, c2 = 0.f, c3 = 0.f, st = 0.f, sy = 0.f;
    #pragma unroll
    for (int s = 0; s < NS / 32; ++s) {          // 4 steps
        const int n = 4 * j + 32 * s;
        const float4 a = *(const float4*)(Tb + n);     // ds_read_b128
        const float4 t = *(const float4*)(ytb + n);
        const float4 p = *(const float4*)(ypb + n);
        c1 = fmaf(p.x, a.x, c1); c2 = fmaf(t.x, a.x, c2);
        c3 = fmaf(a.x, a.x, c3); st = fmaf(t.x, t.x, st);
        sy = fmaf(t.x, p.x, sy);
        c1 = fmaf(p.y, a.y, c1); c2 = fmaf(t.y, a.y, c2);
        c3 = fmaf(a.y, a.y, c3); st = fmaf(t.y, t.y, st);
        sy = fmaf(t.y, p.y, sy);
        c1 = fmaf(p.z, a.z, c1); c2 = fmaf(t.z, a.z, c2);
        c3 = fmaf(a.z, a.z, c3); st = fmaf(t.z, t.z, st);
        sy = fmaf(t.z, p.z, sy);
        c1 = fmaf(p.w, a.w, c1); c2 = fmaf(t.w, a.w, c2);
        c3 = fmaf(a.w, a.w, c3); st = fmaf(t.w, t.w, st);
        sy = fmaf(t.w, p.w, sy);
    }
    #pragma unroll
    for (int d = 4; d; d >>= 1) {                // reduce 8 lanes per b
        c1 += __shfl_down(c1, d, 8);
        c2 += __shfl_down(c2, d, 8);
        c3 += __shfl_down(c3, d, 8);
        st += __shfl_down(st, d, 8);
        sy += __shfl_down(sy, d, 8);
    }
    if (j == 0) {
        float* row = p2 + (size_t)g * 160;
        row[0 * 32 + b] = c1;
        row[1 * 32 + b] = c2;
        row[2 * 32 + b] = c3;
        row[3 * 32 + b] = st;
        row[4 * 32 + b] = sy;
    }
}

// ---------------------------------------------------------------------------
// K4a: stage-1 reduce. grid = 64 x 256. Block g sums p2 rows 32g..32g+31.
// ---------------------------------------------------------------------------
__global__ __launch_bounds__(256) void k_finish1(
        const float* __restrict__ p2, float* __restrict__ pr2) {
    const int tid = threadIdx.x, g = blockIdx.x;
    if (tid < 160) {
        float acc = 0.f;
        #pragma unroll
        for (int j = 0; j < 32; ++j) acc += p2[(size_t)(g * 32 + j) * 160 + tid];
        pr2[g * 160 + tid] = acc;
    }
}

// ---------------------------------------------------------------------------
// K4b: stage-2 reduce (64 rows) + closed-form loss. 1 block x 256.
// ---------------------------------------------------------------------------
__global__ __launch_bounds__(256) void k_finish2(
        const float* __restrict__ pr2, float* __restrict__ out) {
    __shared__ float tot[160];
    __shared__ float lb[32];
    const int tid = threadIdx.x;
    if (tid < 160) {
        float acc = 0.f;
        #pragma unroll
        for (int j = 0; j < 64; ++j) acc += pr2[j * 160 + tid];
        tot[tid] = acc;
    }
    __syncthreads();
    if (tid < 32) {
        const float c1 = tot[0 + tid];
        const float c2 = tot[32 + tid];
        const float c3 = tot[64 + tid];
        const float stt = tot[96 + tid];
        const float sty = tot[128 + tid];
        const float a = sty / c1;
        lb[tid] = fmaf(a * a, c3, fmaf(-2.f * a, c2, stt));
    }
    __syncthreads();
    if (tid == 0) {
        float s = 0.f;
        #pragma unroll
        for (int i = 0; i < 32; ++i) s += lb[i];
        out[0] = s * (1.0f / 32.0f);
    }
}

// ===========================================================================
extern "C" void kernel_launch(void* const* d_in, const int* in_sizes, int n_in,
                              void* d_out, int out_size, void* d_ws, size_t ws_size,
                              hipStream_t stream) {
    const float* yp = (const float*)d_in[0];   // y_pred (32, N)
    const float* yt = (const float*)d_in[1];   // y_true (32, N)
    const float* Av = (const float*)d_in[2];   // A_vals (NNZ)
    const int*   Ar = (const int*)d_in[3];     // A_rows (NNZ)
    const int*   Ac = (const int*)d_in[4];     // A_cols (NNZ)
    float* out = (float*)d_out;

    // Workspace: yp_t 33.6MB + yat64 33.6MB + p2 1.3MB + pr2 40KB ≈ 68.6 MB
    // (round-0 proved >= 82.5 MB available).
    float* ws    = (float*)d_ws;
    float* yp_t  = ws;                              // N*32 f32
    float* yat_f = yp_t + (size_t)NGRID * 32;       // N*16 u64 (same bytes)
    unsigned long long* yat64 = (unsigned long long*)yat_f;
    float* p2    = yat_f + (size_t)NGRID * 32;      // 2048*160
    float* pr2   = p2 + 2048 * 160;                 // 64*160

    k_prep<<<1024, 256, 0, stream>>>(yp, yp_t, yat_f);
    k_scatter<<<(NNZ_C * 8) / 256, 256, 0, stream>>>(Av, Ar, Ac, yp_t, yat64);
    k_post<<<2048, 256, 0, stream>>>(yat64, yp, yt, p2);
    k_finish1<<<64, 256, 0, stream>>>(p2, pr2);
    k_finish2<<<1, 256, 0, stream>>>(pr2, out);
}

// Round 6
// 382.875 us; speedup vs baseline: 1.2031x; 1.2031x over previous
//
#include <hip/hip_runtime.h>

// Problem constants (fixed by the reference).
#define NGRID 262144      // N = 64^3 = 2^18
#define NNZ_C 1835008     // 7 * N
#define TP    260         // prep LDS row stride (floats); 260*4 ≡ 0 mod 16
#define NS    128         // k_post n-slice per block
#define TPAD  132         // k_post LDS row stride (floats); 16B-aligned rows

// Fixed-point scale for packed-pair atomic accumulation of yat.
// |value| bound before low-lane overflow: 2^31/2^19 = 4096 (typ |sum| < 50).
#define FPSCALE   524288.0f          // 2^19
#define FPINV     (1.0f / 524288.0f)

// Loss closed form:  loss = mean_b( Stt - 2a*C2 + a^2*C3 ),  a = Sty/C1
//   C1=<yp,yat>  C2=<yt,yat>  C3=<yat,yat>  Stt=<yt,yt>  Sty=<yt,yp>
// SCATTER LAW (R0/R4/R5 measured): time ∝ line-RMW events; one wave
// instruction covering a full 128B line = one event = one full-line HBM
// write-back. Minimum events = NNZ -> R4's 16-lane x u64 single-atomic
// layout (164us) is the floor; its memory pattern is FROZEN here.
// This round attacks the ~135us non-scatter tail: grid-stride scatter
// (one dispatch wave, 2048 blocks), and finish stages folded into k_post
// via atomicAdd into tot[160] (5 launches -> 4).

// ---------------------------------------------------------------------------
// K1: yp transpose (R7-green tile construct) + zero yat; block 0 also zeroes
// tot[160]. grid = 1024 x 256.
// ---------------------------------------------------------------------------
__global__ __launch_bounds__(256) void k_prep(
        const float* __restrict__ yp, float* __restrict__ yp_t,
        float* __restrict__ yat_t, float* __restrict__ tot) {
    __shared__ __align__(16) float T[32 * TP];
    const int tid = threadIdx.x;
    if (blockIdx.x == 0 && tid < 160) tot[tid] = 0.f;
    const int l = tid & 63, w = tid >> 6;
    const size_t n0 = (size_t)blockIdx.x * 256;
    #pragma unroll
    for (int s = 0; s < 8; ++s) {
        const int b = s * 4 + w;                 // unique (s,w) -> 0..31
        const float4 a = *(const float4*)(yp + (size_t)b * NGRID + n0 + 4 * l);
        *(float4*)(&T[b * TP + 4 * l]) = a;      // ds_write_b128, row b
    }
    __syncthreads();
    float4* dst4 = (float4*)(yp_t + n0 * 32);
    float4* yat4 = (float4*)(yat_t + n0 * 32);
    #pragma unroll
    for (int q = 0; q < 8; ++q) {
        const int f = q * 256 + tid;             // float4 index, 0..2047
        const int n = f >> 3;                    // 0..255 local n
        const int bb = 4 * (f & 7);              // base batch of this quad
        float4 v;
        v.x = T[(bb + 0) * TP + n];
        v.y = T[(bb + 1) * TP + n];
        v.z = T[(bb + 2) * TP + n];
        v.w = T[(bb + 3) * TP + n];
        dst4[f] = v;                             // coalesced 1 KB/wave
        yat4[f] = make_float4(0.f, 0.f, 0.f, 0.f);
    }
}

// ---------------------------------------------------------------------------
// K2: COO scatter — R4's proven memory pattern (16 lanes/edge, float2
// gather covering the 128B yp_t line, ONE u64 atomic per lane covering the
// 128B yat line in one instruction), now GRID-STRIDE: 2048 blocks = 8/CU =
// full residency in a single dispatch wave; 56 edge-sweeps per thread.
// ---------------------------------------------------------------------------
__global__ __launch_bounds__(256) void k_scatter(
        const float* __restrict__ vals, const int* __restrict__ rows,
        const int* __restrict__ cols, const float* __restrict__ yp_t,
        unsigned long long* __restrict__ yat64) {
    const int tid = threadIdx.x;
    const int b2 = tid & 15;
    const size_t g0 = ((size_t)blockIdx.x * 256 + tid) >> 4;   // 0..32767
    #pragma unroll 2
    for (int it = 0; it < NNZ_C / 32768; ++it) {               // 56 sweeps
        const size_t e = g0 + (size_t)it * 32768;
        const float v = vals[e];
        const int r = rows[e];
        const int c = cols[e];
        const float2 x2 = *(const float2*)(yp_t + (size_t)c * 32 + 2 * b2);
        const long long i0 = (long long)__float2int_rn(v * x2.x * FPSCALE);
        const long long i1 = (long long)__float2int_rn(v * x2.y * FPSCALE);
        atomicAdd(&yat64[(size_t)r * 16 + b2],
                  (unsigned long long)((i1 << 32) + i0));
    }
}

// ---------------------------------------------------------------------------
// K3: post-pass, mixed-layout. Block g owns n-slice [128g, 128g+128).
//   Phase A: load packed yat tile (128 x 16 u64, coalesced ulonglong2),
//            exact int64 unpack -> f32, LDS transposed T[b][n], TPAD=132.
//   Phase B: thread (b=tid>>3, j=tid&7): 4 float4 steps over n; yt/yp in
//            ORIGINAL (32,N) layout + ds_read_b128 from T; shfl-reduce the
//            8 lanes per batch; owner lanes atomicAdd 5 partials into
//            tot[160] (replaces p2 + two finish launches).
// ---------------------------------------------------------------------------
__global__ __launch_bounds__(256) void k_post(
        const unsigned long long* __restrict__ yat64,
        const float* __restrict__ yp, const float* __restrict__ yt,
        float* __restrict__ tot) {
    __shared__ __align__(16) float T[32 * TPAD];     // 16.9 KB
    const int tid = threadIdx.x;
    const int g = blockIdx.x;                    // 0..2047
    const size_t n0 = (size_t)g * NS;
    const ulonglong2* y2 = (const ulonglong2*)(yat64 + n0 * 16);
    #pragma unroll
    for (int q = 0; q < 4; ++q) {
        const int f = q * 256 + tid;             // 0..1023 (ull2 index)
        const int n = f >> 3;                    // 0..127
        const int b0 = 4 * (f & 7);
        const ulonglong2 pv = y2[f];
        // exact unpack: p = h*2^32 + lo (lo signed); h = (p + 2^31) >> 32
        const int lo0 = (int)(unsigned)pv.x;
        const int hi0 = (int)((pv.x + 0x80000000ULL) >> 32);
        const int lo1 = (int)(unsigned)pv.y;
        const int hi1 = (int)((pv.y + 0x80000000ULL) >> 32);
        T[(b0 + 0) * TPAD + n] = (float)lo0 * FPINV;
        T[(b0 + 1) * TPAD + n] = (float)hi0 * FPINV;
        T[(b0 + 2) * TPAD + n] = (float)lo1 * FPINV;
        T[(b0 + 3) * TPAD + n] = (float)hi1 * FPINV;
    }
    __syncthreads();
    const int b = tid >> 3, j = tid & 7;
    const float* ytb = yt + (size_t)b * NGRID + n0;
    const float* ypb = yp + (size_t)b * NGRID + n0;
    const float* Tb = &T[b * TPAD];
    float c1 = 0.f, c2 = 0.f, c3 = 0.f, st = 0.f, sy = 0.f;
    #pragma unroll
    for (int s = 0; s < NS / 32; ++s) {          // 4 steps
        const int n = 4 * j + 32 * s;
        const float4 a = *(const float4*)(Tb + n);     // ds_read_b128
        const float4 t = *(const float4*)(ytb + n);
        const float4 p = *(const float4*)(ypb + n);
        c1 = fmaf(p.x, a.x, c1); c2 = fmaf(t.x, a.x, c2);
        c3 = fmaf(a.x, a.x, c3); st = fmaf(t.x, t.x, st);
        sy = fmaf(t.x, p.x, sy);
        c1 = fmaf(p.y, a.y, c1); c2 = fmaf(t.y, a.y, c2);
        c3 = fmaf(a.y, a.y, c3); st = fmaf(t.y, t.y, st);
        sy = fmaf(t.y, p.y, sy);
        c1 = fmaf(p.z, a.z, c1); c2 = fmaf(t.z, a.z, c2);
        c3 = fmaf(a.z, a.z, c3); st = fmaf(t.z, t.z, st);
        sy = fmaf(t.z, p.z, sy);
        c1 = fmaf(p.w, a.w, c1); c2 = fmaf(t.w, a.w, c2);
        c3 = fmaf(a.w, a.w, c3); st = fmaf(t.w, t.w, st);
        sy = fmaf(t.w, p.w, sy);
    }
    #pragma unroll
    for (int d = 4; d; d >>= 1) {                // reduce 8 lanes per b
        c1 += __shfl_down(c1, d, 8);
        c2 += __shfl_down(c2, d, 8);
        c3 += __shfl_down(c3, d, 8);
        st += __shfl_down(st, d, 8);
        sy += __shfl_down(sy, d, 8);
    }
    if (j == 0) {
        atomicAdd(&tot[0 * 32 + b], c1);
        atomicAdd(&tot[1 * 32 + b], c2);
        atomicAdd(&tot[2 * 32 + b], c3);
        atomicAdd(&tot[3 * 32 + b], st);
        atomicAdd(&tot[4 * 32 + b], sy);
    }
}

// ---------------------------------------------------------------------------
// K4: closed-form loss from tot[160]. 1 block x 64.
// ---------------------------------------------------------------------------
__global__ __launch_bounds__(64) void k_finish(
        const float* __restrict__ tot, float* __restrict__ out) {
    __shared__ float lb[32];
    const int tid = threadIdx.x;
    if (tid < 32) {
        const float c1 = tot[0 + tid];
        const float c2 = tot[32 + tid];
        const float c3 = tot[64 + tid];
        const float stt = tot[96 + tid];
        const float sty = tot[128 + tid];
        const float a = sty / c1;
        lb[tid] = fmaf(a * a, c3, fmaf(-2.f * a, c2, stt));
    }
    __syncthreads();
    if (tid == 0) {
        float s = 0.f;
        #pragma unroll
        for (int i = 0; i < 32; ++i) s += lb[i];
        out[0] = s * (1.0f / 32.0f);
    }
}

// ===========================================================================
extern "C" void kernel_launch(void* const* d_in, const int* in_sizes, int n_in,
                              void* d_out, int out_size, void* d_ws, size_t ws_size,
                              hipStream_t stream) {
    const float* yp = (const float*)d_in[0];   // y_pred (32, N)
    const float* yt = (const float*)d_in[1];   // y_true (32, N)
    const float* Av = (const float*)d_in[2];   // A_vals (NNZ)
    const int*   Ar = (const int*)d_in[3];     // A_rows (NNZ)
    const int*   Ac = (const int*)d_in[4];     // A_cols (NNZ)
    float* out = (float*)d_out;

    // Workspace: yp_t 33.6MB + yat64 33.6MB + tot 1KB ≈ 67.2 MB
    // (round-0 proved >= 82.5 MB available).
    float* ws    = (float*)d_ws;
    float* yp_t  = ws;                              // N*32 f32
    float* yat_f = yp_t + (size_t)NGRID * 32;       // N*16 u64 (same bytes)
    unsigned long long* yat64 = (unsigned long long*)yat_f;
    float* tot   = yat_f + (size_t)NGRID * 32;      // 160 (+pad)

    k_prep<<<1024, 256, 0, stream>>>(yp, yp_t, yat_f, tot);
    k_scatter<<<2048, 256, 0, stream>>>(Av, Ar, Ac, yp_t, yat64);
    k_post<<<2048, 256, 0, stream>>>(yat64, yp, yt, tot);
    k_finish<<<1, 64, 0, stream>>>(tot, out);
}

// Round 8
// 296.096 us; speedup vs baseline: 1.5557x; 1.2931x over previous
//
#include <hip/hip_runtime.h>

// Problem constants (fixed by the reference).
#define NGRID 262144      // N = 64^3 = 2^18
#define NNZ_C 1835008     // 7 * N
#define TP    260         // prep LDS row stride (floats); 260*4 ≡ 0 mod 16
#define NS    256         // k_post n-slice per block (R3-proven shape)
#define TPAD  260         // k_post LDS row stride (floats), 16B-aligned rows

// Fixed-point scale for packed-pair atomic accumulation of yat.
// |value| bound before low-lane overflow: 2^31/2^19 = 4096 (typ |sum| < 50).
#define FPSCALE   524288.0f          // 2^19
#define FPINV     (1.0f / 524288.0f)

// Loss closed form:  loss = mean_b( Stt - 2a*C2 + a^2*C3 ),  a = Sty/C1
//   C1=<yp,yat>  C2=<yt,yat>  C3=<yat,yat>  Stt=<yt,yt>  Sty=<yt,yp>
// LAWS (measured R0-R6):
//  * scatter: time ∝ line-RMW events; events=NNZ minimum reached by R4's
//    16-lane/edge single-u64-atomic layout (163.8us). FROZEN.
//  * C3 forces yat materialization (not edge-decomposable) -> scatter stays.
//  * never funnel >>1K atomics into few lines (R6: tot[160] cost +80us);
//    spread partials (p2) + tree reduce.
// This round (resubmit; R7 bench was an infra failure): R4 scatter + R3
// post shape (NS=256, 1024 blocks) with u64 unpack + R3 finish stages.
// Attributes R4's +8us tail (NS vs unpack).

// ---------------------------------------------------------------------------
// K1: yp transpose (R7-green tile construct) + zero yat. grid = 1024 x 256.
// ---------------------------------------------------------------------------
__global__ __launch_bounds__(256) void k_prep(
        const float* __restrict__ yp, float* __restrict__ yp_t,
        float* __restrict__ yat_t) {
    __shared__ __align__(16) float T[32 * TP];
    const int tid = threadIdx.x;
    const int l = tid & 63, w = tid >> 6;
    const size_t n0 = (size_t)blockIdx.x * 256;
    #pragma unroll
    for (int s = 0; s < 8; ++s) {
        const int b = s * 4 + w;                 // unique (s,w) -> 0..31
        const float4 a = *(const float4*)(yp + (size_t)b * NGRID + n0 + 4 * l);
        *(float4*)(&T[b * TP + 4 * l]) = a;      // ds_write_b128, row b
    }
    __syncthreads();
    float4* dst4 = (float4*)(yp_t + n0 * 32);
    float4* yat4 = (float4*)(yat_t + n0 * 32);
    #pragma unroll
    for (int q = 0; q < 8; ++q) {
        const int f = q * 256 + tid;             // float4 index, 0..2047
        const int n = f >> 3;                    // 0..255 local n
        const int bb = 4 * (f & 7);              // base batch of this quad
        float4 v;
        v.x = T[(bb + 0) * TP + n];
        v.y = T[(bb + 1) * TP + n];
        v.z = T[(bb + 2) * TP + n];
        v.w = T[(bb + 3) * TP + n];
        dst4[f] = v;                             // coalesced 1 KB/wave
        yat4[f] = make_float4(0.f, 0.f, 0.f, 0.f);
    }
}

// ---------------------------------------------------------------------------
// K2: COO scatter — R4 verbatim (proven 163.8us; events=NNZ floor).
// thread -> (e=tid>>4, b2=tid&15): float2 gather from yp_t row c (16 lanes
// x 8B = full 128B line), fixed-point convert, ONE u64 atomic per lane pair
// (16 lanes x 8B = full 128B yat line in one instruction = one event).
// grid = NNZ*16/256 = 114688 blocks.
// ---------------------------------------------------------------------------
__global__ void k_scatter(const float* __restrict__ vals,
                          const int* __restrict__ rows,
                          const int* __restrict__ cols,
                          const float* __restrict__ yp_t,
                          unsigned long long* __restrict__ yat64) {
    const size_t tid = (size_t)blockIdx.x * blockDim.x + threadIdx.x;
    const int b2 = (int)(tid & 15);
    const size_t e = tid >> 4;
    const float v = vals[e];
    const int r = rows[e];
    const int c = cols[e];
    const float2 x2 = *(const float2*)(yp_t + (size_t)c * 32 + 2 * b2);
    const long long i0 = (long long)__float2int_rn(v * x2.x * FPSCALE);
    const long long i1 = (long long)__float2int_rn(v * x2.y * FPSCALE);
    atomicAdd(&yat64[(size_t)r * 16 + b2],
              (unsigned long long)((i1 << 32) + i0));
}

// ---------------------------------------------------------------------------
// K3: post-pass, mixed-layout (R3 shape: NS=256, 1024 blocks, 33.3KB LDS).
//   Phase A: load packed yat tile (256 x 16 u64, coalesced ulonglong2),
//            exact int64 unpack -> f32, LDS transposed T[b][n], TPAD=260.
//   Phase B: thread (b=tid>>3, j=tid&7): 8 float4 steps over n; yt/yp in
//            ORIGINAL (32,N) layout + ds_read_b128 from T; shfl-reduce the
//            8 lanes per batch; per-block partials to p2 (spread lines).
// ---------------------------------------------------------------------------
__global__ __launch_bounds__(256) void k_post(
        const unsigned long long* __restrict__ yat64,
        const float* __restrict__ yp, const float* __restrict__ yt,
        float* __restrict__ p2) {
    __shared__ __align__(16) float T[32 * TPAD];     // 33.3 KB
    const int tid = threadIdx.x;
    const int g = blockIdx.x;                    // 0..1023
    const size_t n0 = (size_t)g * NS;
    const ulonglong2* y2 = (const ulonglong2*)(yat64 + n0 * 16);
    #pragma unroll
    for (int q = 0; q < 8; ++q) {
        const int f = q * 256 + tid;             // 0..2047 (ull2 index)
        const int n = f >> 3;                    // 0..255
        const int b0 = 4 * (f & 7);
        const ulonglong2 pv = y2[f];
        // exact unpack: p = h*2^32 + lo (lo signed); h = (p + 2^31) >> 32
        const int lo0 = (int)(unsigned)pv.x;
        const int hi0 = (int)((pv.x + 0x80000000ULL) >> 32);
        const int lo1 = (int)(unsigned)pv.y;
        const int hi1 = (int)((pv.y + 0x80000000ULL) >> 32);
        T[(b0 + 0) * TPAD + n] = (float)lo0 * FPINV;
        T[(b0 + 1) * TPAD + n] = (float)hi0 * FPINV;
        T[(b0 + 2) * TPAD + n] = (float)lo1 * FPINV;
        T[(b0 + 3) * TPAD + n] = (float)hi1 * FPINV;
    }
    __syncthreads();
    const int b = tid >> 3, j = tid & 7;
    const float* ytb = yt + (size_t)b * NGRID + n0;
    const float* ypb = yp + (size_t)b * NGRID + n0;
    const float* Tb = &T[b * TPAD];
    float c1 = 0.f, c2 = 0.f, c3 = 0.f, st = 0.f, sy = 0.f;
    #pragma unroll
    for (int s = 0; s < NS / 32; ++s) {          // 8 steps
        const int n = 4 * j + 32 * s;
        const float4 a = *(const float4*)(Tb + n);     // ds_read_b128
        const float4 t = *(const float4*)(ytb + n);
        const float4 p = *(const float4*)(ypb + n);
        c1 = fmaf(p.x, a.x, c1); c2 = fmaf(t.x, a.x, c2);
        c3 = fmaf(a.x, a.x, c3); st = fmaf(t.x, t.x, st);
        sy = fmaf(t.x, p.x, sy);
        c1 = fmaf(p.y, a.y, c1); c2 = fmaf(t.y, a.y, c2);
        c3 = fmaf(a.y, a.y, c3); st = fmaf(t.y, t.y, st);
        sy = fmaf(t.y, p.y, sy);
        c1 = fmaf(p.z, a.z, c1); c2 = fmaf(t.z, a.z, c2);
        c3 = fmaf(a.z, a.z, c3); st = fmaf(t.z, t.z, st);
        sy = fmaf(t.z, p.z, sy);
        c1 = fmaf(p.w, a.w, c1); c2 = fmaf(t.w, a.w, c2);
        c3 = fmaf(a.w, a.w, c3); st = fmaf(t.w, t.w, st);
        sy = fmaf(t.w, p.w, sy);
    }
    #pragma unroll
    for (int d = 4; d; d >>= 1) {                // reduce 8 lanes per b
        c1 += __shfl_down(c1, d, 8);
        c2 += __shfl_down(c2, d, 8);
        c3 += __shfl_down(c3, d, 8);
        st += __shfl_down(st, d, 8);
        sy += __shfl_down(sy, d, 8);
    }
    if (j == 0) {
        float* row = p2 + (size_t)g * 160;
        row[0 * 32 + b] = c1;
        row[1 * 32 + b] = c2;
        row[2 * 32 + b] = c3;
        row[3 * 32 + b] = st;
        row[4 * 32 + b] = sy;
    }
}

// ---------------------------------------------------------------------------
// K4a: stage-1 reduce. grid = 32 x 256. Block g sums p2 rows 32g..32g+31.
// ---------------------------------------------------------------------------
__global__ __launch_bounds__(256) void k_finish1(
        const float* __restrict__ p2, float* __restrict__ pr2) {
    const int tid = threadIdx.x, g = blockIdx.x;
    if (tid < 160) {
        float acc = 0.f;
        #pragma unroll
        for (int j = 0; j < 32; ++j) acc += p2[(size_t)(g * 32 + j) * 160 + tid];
        pr2[g * 160 + tid] = acc;
    }
}

// ---------------------------------------------------------------------------
// K4b: stage-2 reduce (32 rows) + closed-form loss. 1 block x 256.
// ---------------------------------------------------------------------------
__global__ __launch_bounds__(256) void k_finish2(
        const float* __restrict__ pr2, float* __restrict__ out) {
    __shared__ float tot[160];
    __shared__ float lb[32];
    const int tid = threadIdx.x;
    if (tid < 160) {
        float acc = 0.f;
        #pragma unroll
        for (int j = 0; j < 32; ++j) acc += pr2[j * 160 + tid];
        tot[tid] = acc;
    }
    __syncthreads();
    if (tid < 32) {
        const float c1 = tot[0 + tid];
        const float c2 = tot[32 + tid];
        const float c3 = tot[64 + tid];
        const float stt = tot[96 + tid];
        const float sty = tot[128 + tid];
        const float a = sty / c1;
        lb[tid] = fmaf(a * a, c3, fmaf(-2.f * a, c2, stt));
    }
    __syncthreads();
    if (tid == 0) {
        float s = 0.f;
        #pragma unroll
        for (int i = 0; i < 32; ++i) s += lb[i];
        out[0] = s * (1.0f / 32.0f);
    }
}

// ===========================================================================
extern "C" void kernel_launch(void* const* d_in, const int* in_sizes, int n_in,
                              void* d_out, int out_size, void* d_ws, size_t ws_size,
                              hipStream_t stream) {
    const float* yp = (const float*)d_in[0];   // y_pred (32, N)
    const float* yt = (const float*)d_in[1];   // y_true (32, N)
    const float* Av = (const float*)d_in[2];   // A_vals (NNZ)
    const int*   Ar = (const int*)d_in[3];     // A_rows (NNZ)
    const int*   Ac = (const int*)d_in[4];     // A_cols (NNZ)
    float* out = (float*)d_out;

    // Workspace: yp_t 33.6MB + yat64 33.6MB + p2 640KB + pr2 20KB ≈ 68 MB
    // (round-0 proved >= 82.5 MB available).
    float* ws    = (float*)d_ws;
    float* yp_t  = ws;                              // N*32 f32
    float* yat_f = yp_t + (size_t)NGRID * 32;       // N*16 u64 (same bytes)
    unsigned long long* yat64 = (unsigned long long*)yat_f;
    float* p2    = yat_f + (size_t)NGRID * 32;      // 1024*160
    float* pr2   = p2 + 1024 * 160;                 // 32*160

    k_prep<<<1024, 256, 0, stream>>>(yp, yp_t, yat_f);
    k_scatter<<<(NNZ_C * 16) / 256, 256, 0, stream>>>(Av, Ar, Ac, yp_t, yat64);
    k_post<<<1024, 256, 0, stream>>>(yat64, yp, yt, p2);
    k_finish1<<<32, 256, 0, stream>>>(p2, pr2);
    k_finish2<<<1, 256, 0, stream>>>(pr2, out);
}